// Round 6
// baseline (152.534 us; speedup 1.0000x reference)
//
#include <hip/hip_runtime.h>

#define SEQ 2048
#define DM 1024

typedef __attribute__((ext_vector_type(8))) short bs8;
typedef __attribute__((ext_vector_type(4))) float vf4;
typedef __attribute__((ext_vector_type(4))) unsigned int vu4;

__device__ __forceinline__ unsigned short bf16u(float f) {
  unsigned int u = __float_as_uint(f);
  u = (u + 0x7fffu + ((u >> 16) & 1u)) >> 16;
  return (unsigned short)u;
}

__device__ __forceinline__ unsigned int cvt_pk(float lo, float hi) {
  unsigned int r;
  asm("v_cvt_pk_bf16_f32 %0, %1, %2" : "=v"(r) : "v"(lo), "v"(hi));
  return r;
}

__device__ __forceinline__ float fexp2(float x) {
  float r;
  asm("v_exp_f32 %0, %1" : "=v"(r) : "v"(x));
  return r;
}

__device__ __forceinline__ void gload16(const unsigned short* g, unsigned short* l) {
  __builtin_amdgcn_global_load_lds(
      (const __attribute__((address_space(1))) unsigned int*)g,
      (__attribute__((address_space(3))) unsigned int*)l, 16, 0, 0);
}

// ---- combine: Cqk rows 0..127 = Cq (h*8+r), 128..255 = Ck; hi/lo bf16 out ----
__global__ void k_combine(const float* __restrict__ Wq, const float* __restrict__ Wk,
                          const float* __restrict__ Bm,
                          unsigned short* __restrict__ Ch, unsigned short* __restrict__ Cl) {
  int e = blockIdx.x * 256 + threadIdx.x;
  int which = e >> 17;
  int rem = e & 131071;
  int hr = rem >> 10;
  int j = rem & 1023;
  int h = hr >> 3, r = hr & 7;
  const float* W = which ? Wk : Wq;
  float acc = 0.f;
  #pragma unroll 8
  for (int d = 0; d < 64; d++) {
    int gd = h * 64 + d;
    acc += Bm[gd * 8 + r] * W[gd * 1024 + j];
  }
  size_t idx = (size_t)(which * 128 + hr) * 1024 + j;
  unsigned short h16 = bf16u(acc);
  float hf = __uint_as_float(((unsigned int)h16) << 16);
  Ch[idx] = h16;
  Cl[idx] = bf16u(acc - hf);
}

// ---- f32 -> bf16 ----
__global__ void k_cvt(const float* __restrict__ in, unsigned short* __restrict__ out, int n4) {
  int i = blockIdx.x * 256 + threadIdx.x;
  if (i >= n4) return;
  float4 v = ((const float4*)in)[i];
  ushort4 o;
  o.x = bf16u(v.x); o.y = bf16u(v.y); o.z = bf16u(v.z); o.w = bf16u(v.w);
  ((ushort4*)out)[i] = o;
}

// ---- f32 -> bf16 hi + lo residual ----
__global__ void k_cvt_hl(const float* __restrict__ in, unsigned short* __restrict__ oh,
                         unsigned short* __restrict__ ol, int n4) {
  int i = blockIdx.x * 256 + threadIdx.x;
  if (i >= n4) return;
  float4 v = ((const float4*)in)[i];
  float f[4] = {v.x, v.y, v.z, v.w};
  ushort4 hv, lv;
  unsigned short hs[4], ls[4];
  #pragma unroll
  for (int j = 0; j < 4; j++) {
    unsigned short h16 = bf16u(f[j]);
    float hf = __uint_as_float(((unsigned int)h16) << 16);
    hs[j] = h16;
    ls[j] = bf16u(f[j] - hf);
  }
  hv.x = hs[0]; hv.y = hs[1]; hv.z = hs[2]; hv.w = hs[3];
  lv.x = ls[0]; lv.y = ls[1]; lv.z = ls[2]; lv.w = ls[3];
  ((ushort4*)oh)[i] = hv;
  ((ushort4*)ol)[i] = lv;
}

// ---- QKr via MFMA hi/lo (3-term) + fused hilo epilogue ----
// C = x @ Cqk^T, M=4096 N=256 K=1024. 32x64 tile, grid (128,4), 256 thr.
__global__ __launch_bounds__(256) void k_qkr2(
    const unsigned short* __restrict__ Xh, const unsigned short* __restrict__ Xl,
    const unsigned short* __restrict__ Bh_, const unsigned short* __restrict__ Bl_,
    unsigned short* __restrict__ Qhl, unsigned short* __restrict__ Khl) {
  const int K = 1024;
  __shared__ unsigned short SS[12288];        // 24 KB: Ah|Al|Bh|Bl, epilogue-aliased
  unsigned short* Ah = SS;                    // 32 rows x 64
  unsigned short* Al = SS + 2048;
  unsigned short* Bh = SS + 4096;             // 64 rows x 64
  unsigned short* Bl = SS + 8192;
  int t = threadIdx.x, lane = t & 63, w = t >> 6;
  int gg = lane >> 4, r = lane & 15;
  int wm = w & 1, wn = w >> 1;
  int m0 = blockIdx.x * 32, n0 = blockIdx.y * 64;
  vf4 acc[2];
  #pragma unroll
  for (int fn = 0; fn < 2; fn++) acc[fn] = (vf4){0.f, 0.f, 0.f, 0.f};

  int prow = lane >> 3, pslot = lane & 7;
  int arl = w * 8 + prow;
  int akey = (arl ^ (arl >> 3)) & 7;
  const unsigned short* ah_src = Xh + (size_t)(m0 + arl) * K + (pslot ^ akey) * 8;
  const unsigned short* al_src = Xl + (size_t)(m0 + arl) * K + (pslot ^ akey) * 8;
  unsigned short* ah_dst = &Ah[(w * 8) * 64];
  unsigned short* al_dst = &Al[(w * 8) * 64];
  const unsigned short *bh_src[2], *bl_src[2];
  unsigned short *bh_dst[2], *bl_dst[2];
  #pragma unroll
  for (int p = 0; p < 2; p++) {
    int brl = w * 16 + p * 8 + prow;
    int bkey = (brl ^ (brl >> 3)) & 7;
    bh_src[p] = Bh_ + (size_t)(n0 + brl) * K + (pslot ^ bkey) * 8;
    bl_src[p] = Bl_ + (size_t)(n0 + brl) * K + (pslot ^ bkey) * 8;
    bh_dst[p] = &Bh[(w * 16 + p * 8) * 64];
    bl_dst[p] = &Bl[(w * 16 + p * 8) * 64];
  }

  int aoff[2], boff[2][2];
  {
    int arow = wm * 16 + r;
    int key = (arow ^ (arow >> 3)) & 7;
    #pragma unroll
    for (int kk = 0; kk < 2; kk++) aoff[kk] = arow * 64 + ((kk * 4 + gg) ^ key) * 8;
  }
  #pragma unroll
  for (int fn = 0; fn < 2; fn++) {
    int brow = wn * 32 + fn * 16 + r;
    int key = (brow ^ (brow >> 3)) & 7;
    #pragma unroll
    for (int kk = 0; kk < 2; kk++) boff[fn][kk] = brow * 64 + ((kk * 4 + gg) ^ key) * 8;
  }

  for (int k0 = 0; k0 < K; k0 += 64) {
    __syncthreads();
    gload16(ah_src + k0, ah_dst);
    gload16(al_src + k0, al_dst);
    #pragma unroll
    for (int p = 0; p < 2; p++) {
      gload16(bh_src[p] + k0, bh_dst[p]);
      gload16(bl_src[p] + k0, bl_dst[p]);
    }
    __syncthreads();
    bs8 afh[2], afl[2];
    #pragma unroll
    for (int kk = 0; kk < 2; kk++) {
      afh[kk] = *(const bs8*)&Ah[aoff[kk]];
      afl[kk] = *(const bs8*)&Al[aoff[kk]];
    }
    #pragma unroll
    for (int kk = 0; kk < 2; kk++)
      #pragma unroll
      for (int fn = 0; fn < 2; fn++) {
        bs8 bfh = *(const bs8*)&Bh[boff[fn][kk]];
        bs8 bfl = *(const bs8*)&Bl[boff[fn][kk]];
        acc[fn] = __builtin_amdgcn_mfma_f32_16x16x32_bf16(afh[kk], bfh, acc[fn], 0, 0, 0);
        acc[fn] = __builtin_amdgcn_mfma_f32_16x16x32_bf16(afh[kk], bfl, acc[fn], 0, 0, 0);
        acc[fn] = __builtin_amdgcn_mfma_f32_16x16x32_bf16(afl[kk], bfh, acc[fn], 0, 0, 0);
      }
  }

  // ---- epilogue: acc -> LDS f32 tile (stride 65) -> hilo -> Qhl/Khl ----
  __syncthreads();
  float* Sc = (float*)SS;
  #pragma unroll
  for (int fn = 0; fn < 2; fn++)
    #pragma unroll
    for (int j = 0; j < 4; j++)
      Sc[(wm * 16 + gg * 4 + j) * 65 + wn * 32 + fn * 16 + r] = acc[fn][j];
  __syncthreads();

  int g = t >> 5, xr = t & 31;
  const float* srcrow = &Sc[xr * 65 + g * 8];
  int side = (n0 >= 128) ? 1 : 0;
  int hh = ((n0 & 127) >> 3) + g;
  const float sc = side ? 1.0f : (1.4426950408889634f * 0.35355339059327373f);
  unsigned short hs[8], ls[8];
  #pragma unroll
  for (int j = 0; j < 8; j++) {
    float fs = srcrow[j] * sc;
    unsigned short h16 = bf16u(fs);
    float hf = __uint_as_float(((unsigned int)h16) << 16);
    hs[j] = h16;
    ls[j] = bf16u(fs - hf);
  }
  uint4 hv = {(unsigned int)hs[0] | ((unsigned int)hs[1] << 16),
              (unsigned int)hs[2] | ((unsigned int)hs[3] << 16),
              (unsigned int)hs[4] | ((unsigned int)hs[5] << 16),
              (unsigned int)hs[6] | ((unsigned int)hs[7] << 16)};
  uint4 lv = {(unsigned int)ls[0] | ((unsigned int)ls[1] << 16),
              (unsigned int)ls[2] | ((unsigned int)ls[3] << 16),
              (unsigned int)ls[4] | ((unsigned int)ls[5] << 16),
              (unsigned int)ls[6] | ((unsigned int)ls[7] << 16)};
  unsigned short* dst = (side ? Khl : Qhl) + ((size_t)hh * 4096 + (m0 + xr)) * 16;
  *(uint4*)dst = hv;
  *(uint4*)(dst + 8) = lv;
}

// ---- bf16 MFMA GEMM, 128x64 tile, BK=64, global_load_lds staging ----
// OUT: 0 = f32 C[M][N]; 2 = bf16 transposed C^T[N][M]
template<int OUT>
__global__ __launch_bounds__(256) void k_gemm128(const unsigned short* __restrict__ A,
    const unsigned short* __restrict__ W, void* __restrict__ Cout, int M, int N, int K) {
  __shared__ unsigned short Ah[128 * 64];     // 16 KB
  __shared__ unsigned short Bh[64 * 64];      // 8 KB
  int t = threadIdx.x, lane = t & 63, w = t >> 6;
  int gg = lane >> 4, r = lane & 15;
  int m0 = blockIdx.x * 128, n0 = blockIdx.y * 64;
  vf4 acc[2][4];
  #pragma unroll
  for (int i = 0; i < 2; i++)
    #pragma unroll
    for (int j = 0; j < 4; j++) acc[i][j] = (vf4){0.f, 0.f, 0.f, 0.f};

  int prow = lane >> 3, pslot = lane & 7;
  const unsigned short* asrc[4];
  unsigned short* aldst[4];
  #pragma unroll
  for (int p = 0; p < 4; p++) {
    int rr = w * 32 + p * 8 + prow;
    int c = pslot ^ ((rr ^ (rr >> 3)) & 7);
    asrc[p] = &A[(size_t)(m0 + rr) * K + c * 8];
    aldst[p] = &Ah[(w * 32 + p * 8) * 64];
  }
  const unsigned short* bsrc[2];
  unsigned short* bldst[2];
  #pragma unroll
  for (int p = 0; p < 2; p++) {
    int rn = w * 16 + p * 8 + prow;
    int c = pslot ^ ((rn ^ (rn >> 3)) & 7);
    bsrc[p] = &W[(size_t)(n0 + rn) * K + c * 8];
    bldst[p] = &Bh[(w * 16 + p * 8) * 64];
  }

  int aoff[2][2], boff[4][2];
  #pragma unroll
  for (int fm = 0; fm < 2; fm++) {
    int arow = w * 32 + fm * 16 + r;
    int key = (arow ^ (arow >> 3)) & 7;
    #pragma unroll
    for (int kk = 0; kk < 2; kk++)
      aoff[fm][kk] = arow * 64 + ((kk * 4 + gg) ^ key) * 8;
  }
  #pragma unroll
  for (int fn = 0; fn < 4; fn++) {
    int brow = fn * 16 + r;
    int key = (brow ^ (brow >> 3)) & 7;
    #pragma unroll
    for (int kk = 0; kk < 2; kk++)
      boff[fn][kk] = brow * 64 + ((kk * 4 + gg) ^ key) * 8;
  }

  for (int k0 = 0; k0 < K; k0 += 64) {
    __syncthreads();
    #pragma unroll
    for (int p = 0; p < 4; p++) gload16(asrc[p] + k0, aldst[p]);
    #pragma unroll
    for (int p = 0; p < 2; p++) gload16(bsrc[p] + k0, bldst[p]);
    __syncthreads();
    bs8 af[2][2], bf[4][2];
    #pragma unroll
    for (int fm = 0; fm < 2; fm++)
      #pragma unroll
      for (int kk = 0; kk < 2; kk++) af[fm][kk] = *(const bs8*)&Ah[aoff[fm][kk]];
    #pragma unroll
    for (int fn = 0; fn < 4; fn++)
      #pragma unroll
      for (int kk = 0; kk < 2; kk++) bf[fn][kk] = *(const bs8*)&Bh[boff[fn][kk]];
    #pragma unroll
    for (int kk = 0; kk < 2; kk++)
      #pragma unroll
      for (int fm = 0; fm < 2; fm++)
        #pragma unroll
        for (int fn = 0; fn < 4; fn++)
          acc[fm][fn] = __builtin_amdgcn_mfma_f32_16x16x32_bf16(af[fm][kk], bf[fn][kk], acc[fm][fn], 0, 0, 0);
  }

  #pragma unroll
  for (int fm = 0; fm < 2; fm++)
    #pragma unroll
    for (int fn = 0; fn < 4; fn++) {
      if (OUT == 2) {
        int n = n0 + fn * 16 + r;
        int m = m0 + w * 32 + fm * 16 + gg * 4;
        ushort4 st = {bf16u(acc[fm][fn][0]), bf16u(acc[fm][fn][1]),
                      bf16u(acc[fm][fn][2]), bf16u(acc[fm][fn][3])};
        *(ushort4*)&((unsigned short*)Cout)[(size_t)n * M + m] = st;
      } else {
        #pragma unroll
        for (int j = 0; j < 4; j++) {
          int m = m0 + w * 32 + fm * 16 + gg * 4 + j;
          int n = n0 + fn * 16 + r;
          ((float*)Cout)[(size_t)m * N + n] = acc[fm][fn][j];
        }
      }
    }
}

// ---- fused low-rank flash attention ----
// v6: v5 structure, loop reordered so V staging latency hides under QK^T+softmax
// (QK^T and softmax never read VT; only PV does). K frags prefetched one chunk
// ahead in registers (drained by barrier2, so QK^T needs no waitcnt).
__global__ __launch_bounds__(256, 6) void k_attn(const unsigned short* __restrict__ Qhl,
    const unsigned short* __restrict__ Khl, const unsigned short* __restrict__ Vt,
    unsigned short* __restrict__ AO) {
  int bx = blockIdx.x;
  int qt = bx & 63, h = (bx >> 6) & 15, b = bx >> 10;
  int t = threadIdx.x, lane = t & 63, w = t >> 6;
  int wq = w & 1, kvg = w >> 1;
  int gg = lane >> 4, r = lane & 15;

  __shared__ unsigned short VT[2][4096];       // 16 KB: [kvg][64d x 64kv]

  int qglob = b * 2048 + qt * 32 + wq * 16 + r;
  bs8 bq = {0, 0, 0, 0, 0, 0, 0, 0};
  if (gg != 3)
    bq = *(const bs8*)&Qhl[((size_t)h * 4096 + qglob) * 16 + (gg == 2 ? 8 : 0)];

  // K fragment 32-bit element offset off uniform Khl
  unsigned int kbase = ((unsigned int)(h * 4096 + b * 2048 + kvg * 1024
                        + (r >> 2) * 8 + (r & 3)) << 4) + ((gg == 1) ? 8u : 0u);

  // V staging: 32-bit element offsets off uniform Vt; LDS dest wave-linear.
  int srow = lane >> 3, sslot = lane & 7;
  unsigned int voff[4];
  #pragma unroll
  for (int c = 0; c < 4; c++) {
    int d = wq * 32 + c * 8 + srow;
    int key = (d ^ (d >> 2)) & 7;
    voff[c] = (unsigned int)((h * 64 + d) * 4096 + b * 2048 + kvg * 1024
                             + (sslot ^ key) * 8);
  }

  // PV read offsets (constant per lane)
  int pvoff[2][4];
  #pragma unroll
  for (int sl = 0; sl < 2; sl++)
    #pragma unroll
    for (int fn = 0; fn < 4; fn++) {
      int row = 4 * r + fn;
      int key = (row ^ (row >> 2)) & 7;
      pvoff[sl][fn] = row * 64 + ((sl * 4 + gg) ^ key) * 8;
    }

  float mrun = -INFINITY;
  vf4 acc[4];
  #pragma unroll
  for (int i = 0; i < 4; i++) acc[i] = (vf4){0.f, 0.f, 0.f, 0.f};
  vf4 accs = (vf4){0.f, 0.f, 0.f, 0.f};        // row-sum accumulator (l), MFMA ones-B

  const bs8 ones = (bs8){16256, 16256, 16256, 16256, 16256, 16256, 16256, 16256}; // bf16 1.0

  // prologue: K frags for chunk 0
  bs8 af0 = *(const bs8*)(Khl + kbase);
  bs8 af1 = *(const bs8*)(Khl + kbase + 512);
  bs8 af2 = *(const bs8*)(Khl + kbase + 64);
  bs8 af3 = *(const bs8*)(Khl + kbase + 576);

  for (int kc = 0; kc < 16; kc++) {
    __syncthreads();                           // prev chunk's VT reads complete
    // issue V staging for this chunk; latency hides under QK^T + softmax below
    #pragma unroll
    for (int c = 0; c < 4; c++)
      gload16(Vt + voff[c] + (unsigned int)(kc * 64), &VT[kvg][(wq * 32 + c * 8) * 64]);

    // QK^T — af was drained at the previous barrier; no waitcnt needed here
    vf4 z = (vf4){0.f, 0.f, 0.f, 0.f};
    __builtin_amdgcn_s_setprio(1);
    vf4 s0 = __builtin_amdgcn_mfma_f32_16x16x32_bf16(af0, bq, z, 0, 0, 0);
    vf4 s1 = __builtin_amdgcn_mfma_f32_16x16x32_bf16(af1, bq, z, 0, 0, 0);
    vf4 s2 = __builtin_amdgcn_mfma_f32_16x16x32_bf16(af2, bq, z, 0, 0, 0);
    vf4 s3 = __builtin_amdgcn_mfma_f32_16x16x32_bf16(af3, bq, z, 0, 0, 0);
    __builtin_amdgcn_s_setprio(0);

    // prefetch next chunk's K frags (arrive by barrier2; consumed next iter)
    {
      unsigned int nco = (unsigned int)(((kc < 15) ? kc + 1 : 15) * 1024);
      const unsigned short* kpn = Khl + kbase + nco;
      af0 = *(const bs8*)(kpn);
      af1 = *(const bs8*)(kpn + 512);
      af2 = *(const bs8*)(kpn + 64);
      af3 = *(const bs8*)(kpn + 576);
    }

    float p[16];
    #pragma unroll
    for (int j = 0; j < 4; j++) {
      p[0 + j] = s0[j]; p[4 + j] = s1[j]; p[8 + j] = s2[j]; p[12 + j] = s3[j];
    }
    float cm0 = fmaxf(fmaxf(p[0],  p[1]),  p[2]);
    float cm1 = fmaxf(fmaxf(p[3],  p[4]),  p[5]);
    float cm2 = fmaxf(fmaxf(p[6],  p[7]),  p[8]);
    float cm3 = fmaxf(fmaxf(p[9],  p[10]), p[11]);
    float cm4 = fmaxf(fmaxf(p[12], p[13]), p[14]);
    float cmax = fmaxf(fmaxf(fmaxf(cm0, cm1), cm2),
                       fmaxf(fmaxf(cm3, cm4), p[15]));
    cmax = fmaxf(cmax, __shfl_xor(cmax, 16));
    cmax = fmaxf(cmax, __shfl_xor(cmax, 32));

    if (!__all(cmax <= mrun + 8.f)) {
      float mnew = fmaxf(mrun, cmax);
      float alpha = fexp2(mrun - mnew);
      float al[4];
      #pragma unroll
      for (int j = 0; j < 4; j++) al[j] = __shfl(alpha, gg * 4 + j);
      #pragma unroll
      for (int fn = 0; fn < 4; fn++) {
        acc[fn][0] *= al[0]; acc[fn][1] *= al[1];
        acc[fn][2] *= al[2]; acc[fn][3] *= al[3];
      }
      accs[0] *= al[0]; accs[1] *= al[1];
      accs[2] *= al[2]; accs[3] *= al[3];
      mrun = mnew;
    }

    #pragma unroll
    for (int i = 0; i < 16; i++) p[i] = fexp2(p[i] - mrun);

    vu4 a0 = {cvt_pk(p[0],  p[1]),  cvt_pk(p[2],  p[3]),
              cvt_pk(p[8],  p[9]),  cvt_pk(p[10], p[11])};
    vu4 a1 = {cvt_pk(p[4],  p[5]),  cvt_pk(p[6],  p[7]),
              cvt_pk(p[12], p[13]), cvt_pk(p[14], p[15])};
    bs8 apv0 = __builtin_bit_cast(bs8, a0);
    bs8 apv1 = __builtin_bit_cast(bs8, a1);

    __syncthreads();                           // VT(kc) staged; nf arrived

    const unsigned short* vb = &VT[kvg][0];
    __builtin_amdgcn_s_setprio(1);
    #pragma unroll
    for (int sl = 0; sl < 2; sl++) {
      bs8 a = sl ? apv1 : apv0;
      #pragma unroll
      for (int fn = 0; fn < 4; fn++) {
        bs8 bv = *(const bs8*)&vb[pvoff[sl][fn]];
        acc[fn] = __builtin_amdgcn_mfma_f32_16x16x32_bf16(a, bv, acc[fn], 0, 0, 0);
      }
    }
    accs = __builtin_amdgcn_mfma_f32_16x16x32_bf16(apv0, ones, accs, 0, 0, 0);
    accs = __builtin_amdgcn_mfma_f32_16x16x32_bf16(apv1, ones, accs, 0, 0, 0);
    __builtin_amdgcn_s_setprio(0);
  }

  // ---- in-LDS flash merge: group 1 deposits, group 0 combines ----
  __syncthreads();                              // all reads of VT done
  float* Lm = (float*)&VT[0][0];                // [32] per q-row max
  float* Ll = Lm + 32;                          // [32] per q-row l
  float* La = Lm + 64;                          // [128 lanes] stride 20 floats
  if (kvg == 1) {
    if (gg == 0) Lm[wq * 16 + r] = mrun;
    if (r == 0) {
      #pragma unroll
      for (int j = 0; j < 4; j++) Ll[wq * 16 + gg * 4 + j] = accs[j];
    }
    float* dst = &La[(wq * 64 + lane) * 20];
    #pragma unroll
    for (int fn = 0; fn < 4; fn++) *(vf4*)(dst + fn * 4) = acc[fn];
  }
  __syncthreads();
  if (kvg == 1) return;

  float m1 = Lm[wq * 16 + r];
  float mx = fmaxf(mrun, m1);
  float e0 = fexp2(mrun - mx), e1 = fexp2(m1 - mx);
  float al0[4], al1[4], l1[4];
  #pragma unroll
  for (int j = 0; j < 4; j++) {
    al0[j] = __shfl(e0, gg * 4 + j);
    al1[j] = __shfl(e1, gg * 4 + j);
    l1[j] = Ll[wq * 16 + gg * 4 + j];
  }
  const float* src = &La[(wq * 64 + lane) * 20];
  #pragma unroll
  for (int fn = 0; fn < 4; fn++) {
    vf4 o1 = *(const vf4*)(src + fn * 4);
    #pragma unroll
    for (int j = 0; j < 4; j++)
      acc[fn][j] = acc[fn][j] * al0[j] + o1[j] * al1[j];
  }
  #pragma unroll
  for (int j = 0; j < 4; j++) accs[j] = accs[j] * al0[j] + l1[j] * al1[j];

  float li[4];
  #pragma unroll
  for (int j = 0; j < 4; j++) li[j] = 1.f / accs[j];
  #pragma unroll
  for (int j = 0; j < 4; j++) {
    uint2 o;
    o.x = cvt_pk(acc[0][j] * li[j], acc[1][j] * li[j]);
    o.y = cvt_pk(acc[2][j] * li[j], acc[3][j] * li[j]);
    int qq = qt * 32 + wq * 16 + gg * 4 + j;
    *(uint2*)&AO[((size_t)b * SEQ + qq) * 1024 + h * 64 + 4 * r] = o;
  }
}

extern "C" void kernel_launch(void* const* d_in, const int* in_sizes, int n_in,
                              void* d_out, int out_size, void* d_ws, size_t ws_size,
                              hipStream_t stream) {
  const float* x  = (const float*)d_in[0];
  const float* Wq = (const float*)d_in[1];
  const float* Wk = (const float*)d_in[2];
  const float* Wv = (const float*)d_in[3];
  const float* Wo = (const float*)d_in[4];
  const float* Bm = (const float*)d_in[5];
  float* out = (float*)d_out;

  char* ws = (char*)d_ws;
  unsigned short* Cqkh = (unsigned short*)ws;  ws += (size_t)256 * 1024 * 2;     // 0.5 MB
  unsigned short* Cqkl = (unsigned short*)ws;  ws += (size_t)256 * 1024 * 2;     // 0.5 MB
  unsigned short* xh  = (unsigned short*)ws;   ws += (size_t)4096 * 1024 * 2;    // 8 MB
  unsigned short* Wvh = (unsigned short*)ws;   ws += (size_t)1024 * 1024 * 2;    // 2 MB
  unsigned short* Woh = (unsigned short*)ws;   ws += (size_t)1024 * 1024 * 2;    // 2 MB
  unsigned short* Vt  = (unsigned short*)ws;   ws += (size_t)4096 * 1024 * 2;    // 8 MB
  unsigned short* AO  = (unsigned short*)ws;   ws += (size_t)4096 * 1024 * 2;    // 8 MB
  unsigned short* Qhl = (unsigned short*)ws;   ws += (size_t)16 * 4096 * 16 * 2; // 2 MB
  unsigned short* Khl = (unsigned short*)ws;   ws += (size_t)16 * 4096 * 16 * 2; // 2 MB
  // xl aliases AO: xl is dead after k_qkr2; AO is first written by k_attn later.
  unsigned short* xl = AO;

  k_combine<<<1024, 256, 0, stream>>>(Wq, Wk, Bm, Cqkh, Cqkl);
  k_cvt_hl<<<4096, 256, 0, stream>>>(x, xh, xl, 1048576);
  k_cvt<<<1024, 256, 0, stream>>>(Wv, Wvh, 262144);
  k_cvt<<<1024, 256, 0, stream>>>(Wo, Woh, 262144);
  // QKr (full-K) on the matrix pipe, 3-term hi/lo, fused hilo epilogue
  k_qkr2<<<dim3(128, 4), 256, 0, stream>>>(xh, xl, Cqkh, Cqkl, Qhl, Khl);
  // Vt[1024][4096] = (x @ Wv^T)^T
  k_gemm128<2><<<dim3(32, 16), 256, 0, stream>>>(xh, Wvh, (void*)Vt, 4096, 1024, 1024);
  k_attn<<<2048, 256, 0, stream>>>(Qhl, Khl, Vt, AO);
  // out = AO @ Wo^T
  k_gemm128<0><<<dim3(32, 16), 256, 0, stream>>>(AO, Woh, (void*)out, 4096, 1024, 1024);
}

// Round 7
// 117.059 us; speedup vs baseline: 1.3031x; 1.3031x over previous
//
#include <hip/hip_runtime.h>

#define SEQ 2048
#define DM 1024

typedef __attribute__((ext_vector_type(8))) short bs8;
typedef __attribute__((ext_vector_type(4))) float vf4;
typedef __attribute__((ext_vector_type(4))) unsigned int vu4;

__device__ __forceinline__ unsigned short bf16u(float f) {
  unsigned int u = __float_as_uint(f);
  u = (u + 0x7fffu + ((u >> 16) & 1u)) >> 16;
  return (unsigned short)u;
}

__device__ __forceinline__ unsigned int cvt_pk(float lo, float hi) {
  unsigned int r;
  asm("v_cvt_pk_bf16_f32 %0, %1, %2" : "=v"(r) : "v"(lo), "v"(hi));
  return r;
}

__device__ __forceinline__ float fexp2(float x) {
  float r;
  asm("v_exp_f32 %0, %1" : "=v"(r) : "v"(x));
  return r;
}

__device__ __forceinline__ void gload16(const unsigned short* g, unsigned short* l) {
  __builtin_amdgcn_global_load_lds(
      (const __attribute__((address_space(1))) unsigned int*)g,
      (__attribute__((address_space(3))) unsigned int*)l, 16, 0, 0);
}

// ---- combine: Cqk rows 0..127 = Cq (h*8+r), 128..255 = Ck; hi/lo bf16 out ----
__global__ void k_combine(const float* __restrict__ Wq, const float* __restrict__ Wk,
                          const float* __restrict__ Bm,
                          unsigned short* __restrict__ Ch, unsigned short* __restrict__ Cl) {
  int e = blockIdx.x * 256 + threadIdx.x;
  int which = e >> 17;
  int rem = e & 131071;
  int hr = rem >> 10;
  int j = rem & 1023;
  int h = hr >> 3, r = hr & 7;
  const float* W = which ? Wk : Wq;
  float acc = 0.f;
  #pragma unroll 8
  for (int d = 0; d < 64; d++) {
    int gd = h * 64 + d;
    acc += Bm[gd * 8 + r] * W[gd * 1024 + j];
  }
  size_t idx = (size_t)(which * 128 + hr) * 1024 + j;
  unsigned short h16 = bf16u(acc);
  float hf = __uint_as_float(((unsigned int)h16) << 16);
  Ch[idx] = h16;
  Cl[idx] = bf16u(acc - hf);
}

// ---- f32 -> bf16 ----
__global__ void k_cvt(const float* __restrict__ in, unsigned short* __restrict__ out, int n4) {
  int i = blockIdx.x * 256 + threadIdx.x;
  if (i >= n4) return;
  float4 v = ((const float4*)in)[i];
  ushort4 o;
  o.x = bf16u(v.x); o.y = bf16u(v.y); o.z = bf16u(v.z); o.w = bf16u(v.w);
  ((ushort4*)out)[i] = o;
}

// ---- f32 -> bf16 hi + lo residual ----
__global__ void k_cvt_hl(const float* __restrict__ in, unsigned short* __restrict__ oh,
                         unsigned short* __restrict__ ol, int n4) {
  int i = blockIdx.x * 256 + threadIdx.x;
  if (i >= n4) return;
  float4 v = ((const float4*)in)[i];
  float f[4] = {v.x, v.y, v.z, v.w};
  ushort4 hv, lv;
  unsigned short hs[4], ls[4];
  #pragma unroll
  for (int j = 0; j < 4; j++) {
    unsigned short h16 = bf16u(f[j]);
    float hf = __uint_as_float(((unsigned int)h16) << 16);
    hs[j] = h16;
    ls[j] = bf16u(f[j] - hf);
  }
  hv.x = hs[0]; hv.y = hs[1]; hv.z = hs[2]; hv.w = hs[3];
  lv.x = ls[0]; lv.y = ls[1]; lv.z = ls[2]; lv.w = ls[3];
  ((ushort4*)oh)[i] = hv;
  ((ushort4*)ol)[i] = lv;
}

// ---- QKr via MFMA hi/lo (3-term) + fused hilo epilogue ----
// C = x @ Cqk^T, M=4096 N=256 K=1024. 32x64 tile, grid (128,4), 256 thr.
__global__ __launch_bounds__(256) void k_qkr2(
    const unsigned short* __restrict__ Xh, const unsigned short* __restrict__ Xl,
    const unsigned short* __restrict__ Bh_, const unsigned short* __restrict__ Bl_,
    unsigned short* __restrict__ Qhl, unsigned short* __restrict__ Khl) {
  const int K = 1024;
  __shared__ unsigned short SS[12288];        // 24 KB: Ah|Al|Bh|Bl, epilogue-aliased
  unsigned short* Ah = SS;                    // 32 rows x 64
  unsigned short* Al = SS + 2048;
  unsigned short* Bh = SS + 4096;             // 64 rows x 64
  unsigned short* Bl = SS + 8192;
  int t = threadIdx.x, lane = t & 63, w = t >> 6;
  int gg = lane >> 4, r = lane & 15;
  int wm = w & 1, wn = w >> 1;
  int m0 = blockIdx.x * 32, n0 = blockIdx.y * 64;
  vf4 acc[2];
  #pragma unroll
  for (int fn = 0; fn < 2; fn++) acc[fn] = (vf4){0.f, 0.f, 0.f, 0.f};

  int prow = lane >> 3, pslot = lane & 7;
  int arl = w * 8 + prow;
  int akey = (arl ^ (arl >> 3)) & 7;
  const unsigned short* ah_src = Xh + (size_t)(m0 + arl) * K + (pslot ^ akey) * 8;
  const unsigned short* al_src = Xl + (size_t)(m0 + arl) * K + (pslot ^ akey) * 8;
  unsigned short* ah_dst = &Ah[(w * 8) * 64];
  unsigned short* al_dst = &Al[(w * 8) * 64];
  const unsigned short *bh_src[2], *bl_src[2];
  unsigned short *bh_dst[2], *bl_dst[2];
  #pragma unroll
  for (int p = 0; p < 2; p++) {
    int brl = w * 16 + p * 8 + prow;
    int bkey = (brl ^ (brl >> 3)) & 7;
    bh_src[p] = Bh_ + (size_t)(n0 + brl) * K + (pslot ^ bkey) * 8;
    bl_src[p] = Bl_ + (size_t)(n0 + brl) * K + (pslot ^ bkey) * 8;
    bh_dst[p] = &Bh[(w * 16 + p * 8) * 64];
    bl_dst[p] = &Bl[(w * 16 + p * 8) * 64];
  }

  int aoff[2], boff[2][2];
  {
    int arow = wm * 16 + r;
    int key = (arow ^ (arow >> 3)) & 7;
    #pragma unroll
    for (int kk = 0; kk < 2; kk++) aoff[kk] = arow * 64 + ((kk * 4 + gg) ^ key) * 8;
  }
  #pragma unroll
  for (int fn = 0; fn < 2; fn++) {
    int brow = wn * 32 + fn * 16 + r;
    int key = (brow ^ (brow >> 3)) & 7;
    #pragma unroll
    for (int kk = 0; kk < 2; kk++) boff[fn][kk] = brow * 64 + ((kk * 4 + gg) ^ key) * 8;
  }

  for (int k0 = 0; k0 < K; k0 += 64) {
    __syncthreads();
    gload16(ah_src + k0, ah_dst);
    gload16(al_src + k0, al_dst);
    #pragma unroll
    for (int p = 0; p < 2; p++) {
      gload16(bh_src[p] + k0, bh_dst[p]);
      gload16(bl_src[p] + k0, bl_dst[p]);
    }
    __syncthreads();
    bs8 afh[2], afl[2];
    #pragma unroll
    for (int kk = 0; kk < 2; kk++) {
      afh[kk] = *(const bs8*)&Ah[aoff[kk]];
      afl[kk] = *(const bs8*)&Al[aoff[kk]];
    }
    #pragma unroll
    for (int kk = 0; kk < 2; kk++)
      #pragma unroll
      for (int fn = 0; fn < 2; fn++) {
        bs8 bfh = *(const bs8*)&Bh[boff[fn][kk]];
        bs8 bfl = *(const bs8*)&Bl[boff[fn][kk]];
        acc[fn] = __builtin_amdgcn_mfma_f32_16x16x32_bf16(afh[kk], bfh, acc[fn], 0, 0, 0);
        acc[fn] = __builtin_amdgcn_mfma_f32_16x16x32_bf16(afh[kk], bfl, acc[fn], 0, 0, 0);
        acc[fn] = __builtin_amdgcn_mfma_f32_16x16x32_bf16(afl[kk], bfh, acc[fn], 0, 0, 0);
      }
  }

  // ---- epilogue: acc -> LDS f32 tile (stride 65) -> hilo -> Qhl/Khl ----
  __syncthreads();
  float* Sc = (float*)SS;
  #pragma unroll
  for (int fn = 0; fn < 2; fn++)
    #pragma unroll
    for (int j = 0; j < 4; j++)
      Sc[(wm * 16 + gg * 4 + j) * 65 + wn * 32 + fn * 16 + r] = acc[fn][j];
  __syncthreads();

  int g = t >> 5, xr = t & 31;
  const float* srcrow = &Sc[xr * 65 + g * 8];
  int side = (n0 >= 128) ? 1 : 0;
  int hh = ((n0 & 127) >> 3) + g;
  const float sc = side ? 1.0f : (1.4426950408889634f * 0.35355339059327373f);
  unsigned short hs[8], ls[8];
  #pragma unroll
  for (int j = 0; j < 8; j++) {
    float fs = srcrow[j] * sc;
    unsigned short h16 = bf16u(fs);
    float hf = __uint_as_float(((unsigned int)h16) << 16);
    hs[j] = h16;
    ls[j] = bf16u(fs - hf);
  }
  uint4 hv = {(unsigned int)hs[0] | ((unsigned int)hs[1] << 16),
              (unsigned int)hs[2] | ((unsigned int)hs[3] << 16),
              (unsigned int)hs[4] | ((unsigned int)hs[5] << 16),
              (unsigned int)hs[6] | ((unsigned int)hs[7] << 16)};
  uint4 lv = {(unsigned int)ls[0] | ((unsigned int)ls[1] << 16),
              (unsigned int)ls[2] | ((unsigned int)ls[3] << 16),
              (unsigned int)ls[4] | ((unsigned int)ls[5] << 16),
              (unsigned int)ls[6] | ((unsigned int)ls[7] << 16)};
  unsigned short* dst = (side ? Khl : Qhl) + ((size_t)hh * 4096 + (m0 + xr)) * 16;
  *(uint4*)dst = hv;
  *(uint4*)(dst + 8) = lv;
}

// ---- bf16 MFMA GEMM, 128x64 tile, BK=64, global_load_lds staging ----
// OUT: 0 = f32 C[M][N]; 2 = bf16 transposed C^T[N][M]
template<int OUT>
__global__ __launch_bounds__(256) void k_gemm128(const unsigned short* __restrict__ A,
    const unsigned short* __restrict__ W, void* __restrict__ Cout, int M, int N, int K) {
  __shared__ unsigned short Ah[128 * 64];     // 16 KB
  __shared__ unsigned short Bh[64 * 64];      // 8 KB
  int t = threadIdx.x, lane = t & 63, w = t >> 6;
  int gg = lane >> 4, r = lane & 15;
  int m0 = blockIdx.x * 128, n0 = blockIdx.y * 64;
  vf4 acc[2][4];
  #pragma unroll
  for (int i = 0; i < 2; i++)
    #pragma unroll
    for (int j = 0; j < 4; j++) acc[i][j] = (vf4){0.f, 0.f, 0.f, 0.f};

  int prow = lane >> 3, pslot = lane & 7;
  const unsigned short* asrc[4];
  unsigned short* aldst[4];
  #pragma unroll
  for (int p = 0; p < 4; p++) {
    int rr = w * 32 + p * 8 + prow;
    int c = pslot ^ ((rr ^ (rr >> 3)) & 7);
    asrc[p] = &A[(size_t)(m0 + rr) * K + c * 8];
    aldst[p] = &Ah[(w * 32 + p * 8) * 64];
  }
  const unsigned short* bsrc[2];
  unsigned short* bldst[2];
  #pragma unroll
  for (int p = 0; p < 2; p++) {
    int rn = w * 16 + p * 8 + prow;
    int c = pslot ^ ((rn ^ (rn >> 3)) & 7);
    bsrc[p] = &W[(size_t)(n0 + rn) * K + c * 8];
    bldst[p] = &Bh[(w * 16 + p * 8) * 64];
  }

  int aoff[2][2], boff[4][2];
  #pragma unroll
  for (int fm = 0; fm < 2; fm++) {
    int arow = w * 32 + fm * 16 + r;
    int key = (arow ^ (arow >> 3)) & 7;
    #pragma unroll
    for (int kk = 0; kk < 2; kk++)
      aoff[fm][kk] = arow * 64 + ((kk * 4 + gg) ^ key) * 8;
  }
  #pragma unroll
  for (int fn = 0; fn < 4; fn++) {
    int brow = fn * 16 + r;
    int key = (brow ^ (brow >> 3)) & 7;
    #pragma unroll
    for (int kk = 0; kk < 2; kk++)
      boff[fn][kk] = brow * 64 + ((kk * 4 + gg) ^ key) * 8;
  }

  for (int k0 = 0; k0 < K; k0 += 64) {
    __syncthreads();
    #pragma unroll
    for (int p = 0; p < 4; p++) gload16(asrc[p] + k0, aldst[p]);
    #pragma unroll
    for (int p = 0; p < 2; p++) gload16(bsrc[p] + k0, bldst[p]);
    __syncthreads();
    bs8 af[2][2], bf[4][2];
    #pragma unroll
    for (int fm = 0; fm < 2; fm++)
      #pragma unroll
      for (int kk = 0; kk < 2; kk++) af[fm][kk] = *(const bs8*)&Ah[aoff[fm][kk]];
    #pragma unroll
    for (int fn = 0; fn < 4; fn++)
      #pragma unroll
      for (int kk = 0; kk < 2; kk++) bf[fn][kk] = *(const bs8*)&Bh[boff[fn][kk]];
    #pragma unroll
    for (int kk = 0; kk < 2; kk++)
      #pragma unroll
      for (int fm = 0; fm < 2; fm++)
        #pragma unroll
        for (int fn = 0; fn < 4; fn++)
          acc[fm][fn] = __builtin_amdgcn_mfma_f32_16x16x32_bf16(af[fm][kk], bf[fn][kk], acc[fm][fn], 0, 0, 0);
  }

  #pragma unroll
  for (int fm = 0; fm < 2; fm++)
    #pragma unroll
    for (int fn = 0; fn < 4; fn++) {
      if (OUT == 2) {
        int n = n0 + fn * 16 + r;
        int m = m0 + w * 32 + fm * 16 + gg * 4;
        ushort4 st = {bf16u(acc[fm][fn][0]), bf16u(acc[fm][fn][1]),
                      bf16u(acc[fm][fn][2]), bf16u(acc[fm][fn][3])};
        *(ushort4*)&((unsigned short*)Cout)[(size_t)n * M + m] = st;
      } else {
        #pragma unroll
        for (int j = 0; j < 4; j++) {
          int m = m0 + w * 32 + fm * 16 + gg * 4 + j;
          int n = n0 + fn * 16 + r;
          ((float*)Cout)[(size_t)m * N + n] = acc[fm][fn][j];
        }
      }
    }
}

// ---- fused low-rank flash attention (v2, verified 51 us @ R2) ----
// 256 thr / 4 q-waves, 64-q tile, full 2048 kv per block, double-buffered VT
// (1 barrier/chunk), V+K prefetch at iteration top, row-sum on the MFMA pipe,
// setprio around MFMA clusters. 52 VGPR, no spills.
__global__ __launch_bounds__(256, 4) void k_attn(const unsigned short* __restrict__ Qhl,
    const unsigned short* __restrict__ Khl, const unsigned short* __restrict__ Vt,
    unsigned short* __restrict__ AO) {
  int bx = blockIdx.x;
  int qt = bx & 31, h = (bx >> 5) & 15, b = bx >> 9;
  int t = threadIdx.x, lane = t & 63, w = t >> 6;
  int gg = lane >> 4, r = lane & 15;

  __shared__ unsigned short VT[2][4096];       // 16 KB double-buffered

  int qglob = b * 2048 + qt * 64 + w * 16 + r;
  bs8 bq = {0, 0, 0, 0, 0, 0, 0, 0};
  if (gg != 3)
    bq = *(const bs8*)&Qhl[((size_t)h * 4096 + qglob) * 16 + (gg == 2 ? 8 : 0)];

  const unsigned short* Khead = &Khl[((size_t)h * 4096 + (size_t)b * 2048) * 16];
  int koff = (gg == 1) ? 8 : 0;
  const unsigned short* kp[4];
  #pragma unroll
  for (int kt = 0; kt < 4; kt++) {
    int ks = (kt & 1) * 32 + (r >> 2) * 8 + (kt >> 1) * 4 + (r & 3);
    kp[kt] = Khead + (size_t)ks * 16 + koff;
  }

  int vrow = t >> 2, vcl = t & 3;
  const unsigned short* vsrc = &Vt[(size_t)(h * 64 + vrow) * 4096 + (size_t)b * 2048 + vcl * 16];
  int vkey = (vrow ^ (vrow >> 2)) & 7;
  int sw0 = ((vcl * 2) ^ vkey) * 8;
  int sw1 = ((vcl * 2 + 1) ^ vkey) * 8;

  int pvoff[2][4];
  #pragma unroll
  for (int sl = 0; sl < 2; sl++)
    #pragma unroll
    for (int fn = 0; fn < 4; fn++) {
      int row = 4 * r + fn;
      int key = (row ^ (row >> 2)) & 7;
      pvoff[sl][fn] = row * 64 + ((sl * 4 + gg) ^ key) * 8;
    }

  float mrun = -INFINITY;
  vf4 acc[4];
  #pragma unroll
  for (int i = 0; i < 4; i++) acc[i] = (vf4){0.f, 0.f, 0.f, 0.f};
  vf4 accs = (vf4){0.f, 0.f, 0.f, 0.f};        // row-sum accumulator (l), MFMA ones-B

  const bs8 ones = (bs8){16256, 16256, 16256, 16256, 16256, 16256, 16256, 16256}; // bf16 1.0

  // ---- prologue: chunk 0 V -> VT[0], K frags -> af ----
  uint4 fv0 = *(const uint4*)(vsrc);
  uint4 fv1 = *(const uint4*)(vsrc + 8);
  bs8 af0 = *(const bs8*)(kp[0]);
  bs8 af1 = *(const bs8*)(kp[1]);
  bs8 af2 = *(const bs8*)(kp[2]);
  bs8 af3 = *(const bs8*)(kp[3]);
  {
    unsigned short* vd = &VT[0][vrow * 64];
    *(uint4*)(vd + sw0) = fv0;
    *(uint4*)(vd + sw1) = fv1;
  }
  __syncthreads();

  #pragma unroll 2
  for (int kc = 0; kc < 32; kc++) {
    int nc = kc < 31 ? kc + 1 : 31;
    uint4 nv0 = *(const uint4*)(vsrc + nc * 64);
    uint4 nv1 = *(const uint4*)(vsrc + nc * 64 + 8);
    size_t nb16 = (size_t)nc * 64 * 16;
    bs8 naf0 = *(const bs8*)(kp[0] + nb16);
    bs8 naf1 = *(const bs8*)(kp[1] + nb16);
    bs8 naf2 = *(const bs8*)(kp[2] + nb16);
    bs8 naf3 = *(const bs8*)(kp[3] + nb16);

    vf4 z = (vf4){0.f, 0.f, 0.f, 0.f};
    __builtin_amdgcn_s_setprio(1);
    vf4 s0 = __builtin_amdgcn_mfma_f32_16x16x32_bf16(af0, bq, z, 0, 0, 0);
    vf4 s1 = __builtin_amdgcn_mfma_f32_16x16x32_bf16(af1, bq, z, 0, 0, 0);
    vf4 s2 = __builtin_amdgcn_mfma_f32_16x16x32_bf16(af2, bq, z, 0, 0, 0);
    vf4 s3 = __builtin_amdgcn_mfma_f32_16x16x32_bf16(af3, bq, z, 0, 0, 0);
    __builtin_amdgcn_s_setprio(0);

    float p[16];
    #pragma unroll
    for (int j = 0; j < 4; j++) {
      p[0 + j] = s0[j]; p[4 + j] = s1[j]; p[8 + j] = s2[j]; p[12 + j] = s3[j];
    }
    float cm0 = fmaxf(fmaxf(p[0],  p[1]),  p[2]);
    float cm1 = fmaxf(fmaxf(p[3],  p[4]),  p[5]);
    float cm2 = fmaxf(fmaxf(p[6],  p[7]),  p[8]);
    float cm3 = fmaxf(fmaxf(p[9],  p[10]), p[11]);
    float cm4 = fmaxf(fmaxf(p[12], p[13]), p[14]);
    float cmax = fmaxf(fmaxf(fmaxf(cm0, cm1), cm2),
                       fmaxf(fmaxf(cm3, cm4), p[15]));
    cmax = fmaxf(cmax, __shfl_xor(cmax, 16));
    cmax = fmaxf(cmax, __shfl_xor(cmax, 32));

    if (!__all(cmax <= mrun + 8.f)) {
      float mnew = fmaxf(mrun, cmax);
      float alpha = fexp2(mrun - mnew);
      float al[4];
      #pragma unroll
      for (int j = 0; j < 4; j++) al[j] = __shfl(alpha, gg * 4 + j);
      #pragma unroll
      for (int fn = 0; fn < 4; fn++) {
        acc[fn][0] *= al[0]; acc[fn][1] *= al[1];
        acc[fn][2] *= al[2]; acc[fn][3] *= al[3];
      }
      accs[0] *= al[0]; accs[1] *= al[1];
      accs[2] *= al[2]; accs[3] *= al[3];
      mrun = mnew;
    }

    #pragma unroll
    for (int i = 0; i < 16; i++) p[i] = fexp2(p[i] - mrun);

    vu4 a0 = {cvt_pk(p[0],  p[1]),  cvt_pk(p[2],  p[3]),
              cvt_pk(p[8],  p[9]),  cvt_pk(p[10], p[11])};
    vu4 a1 = {cvt_pk(p[4],  p[5]),  cvt_pk(p[6],  p[7]),
              cvt_pk(p[12], p[13]), cvt_pk(p[14], p[15])};
    bs8 apv0 = __builtin_bit_cast(bs8, a0);
    bs8 apv1 = __builtin_bit_cast(bs8, a1);

    const unsigned short* vb = &VT[kc & 1][0];
    __builtin_amdgcn_s_setprio(1);
    #pragma unroll
    for (int sl = 0; sl < 2; sl++) {
      bs8 a = sl ? apv1 : apv0;
      #pragma unroll
      for (int fn = 0; fn < 4; fn++) {
        bs8 bv = *(const bs8*)&vb[pvoff[sl][fn]];
        acc[fn] = __builtin_amdgcn_mfma_f32_16x16x32_bf16(a, bv, acc[fn], 0, 0, 0);
      }
    }
    accs = __builtin_amdgcn_mfma_f32_16x16x32_bf16(apv0, ones, accs, 0, 0, 0);
    accs = __builtin_amdgcn_mfma_f32_16x16x32_bf16(apv1, ones, accs, 0, 0, 0);
    __builtin_amdgcn_s_setprio(0);

    af0 = naf0; af1 = naf1; af2 = naf2; af3 = naf3;

    if (kc < 31) {
      unsigned short* vd = &VT[(kc + 1) & 1][vrow * 64];
      *(uint4*)(vd + sw0) = nv0;
      *(uint4*)(vd + sw1) = nv1;
      __syncthreads();
    }
  }

  float li[4];
  #pragma unroll
  for (int j = 0; j < 4; j++) li[j] = 1.f / accs[j];
  #pragma unroll
  for (int j = 0; j < 4; j++) {
    uint2 o;
    o.x = cvt_pk(acc[0][j] * li[j], acc[1][j] * li[j]);
    o.y = cvt_pk(acc[2][j] * li[j], acc[3][j] * li[j]);
    int qq = qt * 64 + w * 16 + gg * 4 + j;
    *(uint2*)&AO[((size_t)b * SEQ + qq) * 1024 + h * 64 + 4 * r] = o;
  }
}

extern "C" void kernel_launch(void* const* d_in, const int* in_sizes, int n_in,
                              void* d_out, int out_size, void* d_ws, size_t ws_size,
                              hipStream_t stream) {
  const float* x  = (const float*)d_in[0];
  const float* Wq = (const float*)d_in[1];
  const float* Wk = (const float*)d_in[2];
  const float* Wv = (const float*)d_in[3];
  const float* Wo = (const float*)d_in[4];
  const float* Bm = (const float*)d_in[5];
  float* out = (float*)d_out;

  char* ws = (char*)d_ws;
  unsigned short* Cqkh = (unsigned short*)ws;  ws += (size_t)256 * 1024 * 2;     // 0.5 MB
  unsigned short* Cqkl = (unsigned short*)ws;  ws += (size_t)256 * 1024 * 2;     // 0.5 MB
  unsigned short* xh  = (unsigned short*)ws;   ws += (size_t)4096 * 1024 * 2;    // 8 MB
  unsigned short* Wvh = (unsigned short*)ws;   ws += (size_t)1024 * 1024 * 2;    // 2 MB
  unsigned short* Woh = (unsigned short*)ws;   ws += (size_t)1024 * 1024 * 2;    // 2 MB
  unsigned short* Vt  = (unsigned short*)ws;   ws += (size_t)4096 * 1024 * 2;    // 8 MB
  unsigned short* AO  = (unsigned short*)ws;   ws += (size_t)4096 * 1024 * 2;    // 8 MB
  unsigned short* Qhl = (unsigned short*)ws;   ws += (size_t)16 * 4096 * 16 * 2; // 2 MB
  unsigned short* Khl = (unsigned short*)ws;   ws += (size_t)16 * 4096 * 16 * 2; // 2 MB
  // xl aliases AO: xl is dead after k_qkr2; AO is first written by k_attn later.
  unsigned short* xl = AO;

  k_combine<<<1024, 256, 0, stream>>>(Wq, Wk, Bm, Cqkh, Cqkl);
  k_cvt_hl<<<4096, 256, 0, stream>>>(x, xh, xl, 1048576);
  k_cvt<<<1024, 256, 0, stream>>>(Wv, Wvh, 262144);
  k_cvt<<<1024, 256, 0, stream>>>(Wo, Woh, 262144);
  // QKr (full-K) on the matrix pipe, 3-term hi/lo, fused hilo epilogue
  k_qkr2<<<dim3(128, 4), 256, 0, stream>>>(xh, xl, Cqkh, Cqkl, Qhl, Khl);
  // Vt[1024][4096] = (x @ Wv^T)^T
  k_gemm128<2><<<dim3(32, 16), 256, 0, stream>>>(xh, Wvh, (void*)Vt, 4096, 1024, 1024);
  k_attn<<<1024, 256, 0, stream>>>(Qhl, Khl, Vt, AO);
  // out = AO @ Wo^T
  k_gemm128<0><<<dim3(32, 16), 256, 0, stream>>>(AO, Woh, (void*)out, 4096, 1024, 1024);
}